// Round 6
// baseline (615.360 us; speedup 1.0000x reference)
//
#include <hip/hip_runtime.h>
#include <hip/hip_bf16.h>

// Problem constants
#define BB 32   // batch
#define TT 32   // window
#define NN 64   // num_series
#define CC 64   // inter_dim
#define HH 64   // gru hidden
#define QKD 32  // qk dim
#define HOR 12
#define OUTD (NN*HOR)        // 768
#define KFLAT (NN*CC*TT)     // 131072
#define NBLK 512             // middle kernel grid (co-resident: 51KB LDS, <=2 blk/CU guaranteed)

typedef __attribute__((ext_vector_type(4))) float f32x4;
typedef __attribute__((ext_vector_type(8))) short s16x8;
typedef unsigned short ush;

static __device__ __forceinline__ ush f2bf(float f) {
    unsigned u = __float_as_uint(f);
    unsigned r = (u + 0x7FFFu + ((u >> 16) & 1u)) >> 16;
    return (ush)r;
}
static __device__ __forceinline__ float bf2f(ush h) {
    return __uint_as_float(((unsigned)h) << 16);
}
static __device__ __forceinline__ void split8(const float* f, uint4& hi, uint4& lo) {
    unsigned hh[8], ll[8];
    #pragma unroll
    for (int i = 0; i < 8; ++i) {
        ush h = f2bf(f[i]);
        float hf = bf2f(h);
        hh[i] = h;
        ll[i] = f2bf(f[i] - hf);
    }
    hi = make_uint4(hh[0] | (hh[1] << 16), hh[2] | (hh[3] << 16),
                    hh[4] | (hh[5] << 16), hh[6] | (hh[7] << 16));
    lo = make_uint4(ll[0] | (ll[1] << 16), ll[2] | (ll[3] << 16),
                    ll[4] | (ll[5] << 16), ll[6] | (ll[7] << 16));
}
static __device__ __forceinline__ void gl2lds16(const void* gsrc, void* ldst) {
    __builtin_amdgcn_global_load_lds(
        (const __attribute__((address_space(1))) unsigned int*)gsrc,
        (__attribute__((address_space(3))) unsigned int*)ldst, 16, 0, 0);
}

// one-shot grid barrier #k (counters zeroed by hipMemsetAsync each call)
static __device__ __forceinline__ void gridbar(unsigned* bar, int k) {
    __syncthreads();
    if (threadIdx.x == 0) {
        __threadfence();                         // release prior writes (device scope)
        unsigned* cnt = bar + 2*k;
        unsigned* flg = bar + 2*k + 1;
        unsigned prev = atomicAdd(cnt, 1u);
        if (prev == NBLK - 1u) {
            __threadfence();
            atomicExch(flg, 1u);
        } else {
            while (atomicAdd(flg, 0u) == 0u) __builtin_amdgcn_s_sleep(4);
        }
        __threadfence();                         // acquire
    }
    __syncthreads();
}

struct MidP {
    const float *x, *wih, *whh, *bih, *bhh;
    float* hT;
    const float *wq_w, *wq_b, *wk_w, *wk_b;
    ush *whT_hi, *whT_lo;
    const float *gw0, *wx, *bx;
    float *u, *v;
    const float *gw1; ush *g1h, *g1l;
    const float *gw2; ush *g2h, *g2l;
    const float *cw1; ush *c1h, *c1l;
    const float *cw2; ush *c2h, *c2l;
    const float *cw3; ush *c3h, *c3l;
    const float *lb; float* out;
    const float *gb0, *gb1, *gb2, *cb1, *cb2, *cb3;
    float *bufA, *bufB; ush* flat16;
    unsigned* bar;
};

// ---------------- GCN unit (one (t,b) tile) --------------------------------
template<bool FIRST>
static __device__ void gcn_unit(int tb, const float* fin,
    const ush* gwT_hi, const ush* gwT_lo, const float* u, const float* v,
    const ush* whT_hi, const ush* whT_lo, const float* gb, float* o, char* smem)
{
    ush (*ft_hi)[64]  = (ush(*)[64])smem;
    ush (*ft_lo)[64]  = (ush(*)[64])(smem + 8192);
    ush (*xsT_hi)[64] = (ush(*)[64])(smem + 16384);
    ush (*xsT_lo)[64] = (ush(*)[64])(smem + 24576);
    float* x_l = (float*)(smem + 32768);
    int t = tb >> 5, b = tb & 31;
    int tid = threadIdx.x;
    int w = tid >> 6, l = tid & 63, lm = l & 15, ld = l >> 4;
    __syncthreads();   // previous unit done with smem

    if (FIRST) {
        if (tid < 64) x_l[tid] = fin[(b*TT + t)*NN + tid];
        __syncthreads();
        int d = tid >> 2, nq = tid & 3;
        float ud = u[t*64 + d], vd = v[t*64 + d];
        float vals[16];
        #pragma unroll
        for (int i = 0; i < 16; ++i) vals[i] = x_l[nq*16 + i]*ud + vd;
        #pragma unroll
        for (int h = 0; h < 2; ++h) {
            uint4 hi, lo; split8(&vals[h*8], hi, lo);
            int un = (nq*2 + h) ^ (d & 7);
            *(uint4*)&xsT_hi[d][un*8] = hi;
            *(uint4*)&xsT_lo[d][un*8] = lo;
        }
        __syncthreads();
    } else {
        {
            int row = tid >> 2, c0 = (tid & 3) * 16;
            const float* src = fin + (size_t)tb*4096 + row*64 + c0;
            float f8a[8], f8b[8];
            *(float4*)f8a = *(const float4*)src;       *(float4*)(f8a+4) = *(const float4*)(src+4);
            *(float4*)f8b = *(const float4*)(src+8);   *(float4*)(f8b+4) = *(const float4*)(src+12);
            uint4 hi, lo;
            split8(f8a, hi, lo);
            int u0 = ((c0>>3)) ^ (row & 7);
            *(uint4*)&ft_hi[row][u0*8] = hi; *(uint4*)&ft_lo[row][u0*8] = lo;
            split8(f8b, hi, lo);
            int u1 = ((c0>>3)+1) ^ (row & 7);
            *(uint4*)&ft_hi[row][u1*8] = hi; *(uint4*)&ft_lo[row][u1*8] = lo;
        }
        __syncthreads();
        f32x4 acc[4];
        #pragma unroll
        for (int ct = 0; ct < 4; ++ct) acc[ct] = (f32x4){0.f,0.f,0.f,0.f};
        #pragma unroll
        for (int kc = 0; kc < 2; ++kc) {
            int nrow = w*16 + lm;
            int ux = (kc*4 + ld) ^ (nrow & 7);
            s16x8 xh = *(const s16x8*)&ft_hi[nrow][ux*8];
            s16x8 xl = *(const s16x8*)&ft_lo[nrow][ux*8];
            #pragma unroll
            for (int ct = 0; ct < 4; ++ct) {
                int drow = ct*16 + lm;
                s16x8 yh = *(const s16x8*)&gwT_hi[t*4096 + drow*64 + kc*32 + ld*8];
                s16x8 yl = *(const s16x8*)&gwT_lo[t*4096 + drow*64 + kc*32 + ld*8];
                acc[ct] = __builtin_amdgcn_mfma_f32_16x16x32_bf16(xh, yh, acc[ct], 0, 0, 0);
                acc[ct] = __builtin_amdgcn_mfma_f32_16x16x32_bf16(xh, yl, acc[ct], 0, 0, 0);
                acc[ct] = __builtin_amdgcn_mfma_f32_16x16x32_bf16(xl, yh, acc[ct], 0, 0, 0);
            }
        }
        #pragma unroll
        for (int ct = 0; ct < 4; ++ct) {
            int d = ct*16 + lm;
            int n0 = w*16 + ld*4;
            ush hh[4], llo[4];
            #pragma unroll
            for (int r = 0; r < 4; ++r) {
                float val = acc[ct][r];
                ush h = f2bf(val);
                hh[r] = h; llo[r] = f2bf(val - bf2f(h));
            }
            int un = (n0 >> 3) ^ (d & 7);
            int base = d*64 + un*8 + (n0 & 7);
            *(uint2*)&xsT_hi[0][0 + base] = make_uint2(hh[0]|(hh[1]<<16), hh[2]|(hh[3]<<16));
            *(uint2*)&xsT_lo[0][0 + base] = make_uint2(llo[0]|(llo[1]<<16), llo[2]|(llo[3]<<16));
        }
        __syncthreads();
    }

    f32x4 acc2[4];
    #pragma unroll
    for (int ct = 0; ct < 4; ++ct) acc2[ct] = (f32x4){0.f,0.f,0.f,0.f};
    #pragma unroll
    for (int kc = 0; kc < 2; ++kc) {
        int jrow = w*16 + lm;
        s16x8 wh = *(const s16x8*)&whT_hi[b*4096 + jrow*64 + kc*32 + ld*8];
        s16x8 wl = *(const s16x8*)&whT_lo[b*4096 + jrow*64 + kc*32 + ld*8];
        #pragma unroll
        for (int ct = 0; ct < 4; ++ct) {
            int drow = ct*16 + lm;
            int uy = (kc*4 + ld) ^ (drow & 7);
            s16x8 yh = *(const s16x8*)&xsT_hi[drow][uy*8];
            s16x8 yl = *(const s16x8*)&xsT_lo[drow][uy*8];
            acc2[ct] = __builtin_amdgcn_mfma_f32_16x16x32_bf16(wh, yh, acc2[ct], 0, 0, 0);
            acc2[ct] = __builtin_amdgcn_mfma_f32_16x16x32_bf16(wh, yl, acc2[ct], 0, 0, 0);
            acc2[ct] = __builtin_amdgcn_mfma_f32_16x16x32_bf16(wl, yh, acc2[ct], 0, 0, 0);
        }
    }
    float* oo = o + (size_t)tb*4096;
    #pragma unroll
    for (int ct = 0; ct < 4; ++ct) {
        int d = ct*16 + lm;
        float bias = gb[t*64 + d];
        #pragma unroll
        for (int r = 0; r < 4; ++r) {
            int jj = w*16 + ld*4 + r;
            oo[jj*64 + d] = acc2[ct][r] + bias;
        }
    }
}

// ---------------- conv unit (one (b,n) column) ------------------------------
template<int KW, bool LAST>
static __device__ void conv_unit(int bn, float* g,
    const ush* wch, const ush* wcl, const float* cb, ush* fo, char* smem)
{
    constexpr int P = KW/2, K = KW*64, K32 = KW*2;
    ush (*sh)[64] = (ush(*)[64])smem;
    ush (*sl)[64] = (ush(*)[64])(smem + 8192);
    int tid = threadIdx.x;
    __syncthreads();   // previous unit done with smem
    {
        int t = tid >> 3, c0 = (tid & 7) * 8;
        const float* src = &g[((size_t)t*2048 + bn)*64 + c0];
        float f8[8];
        *(float4*)f8 = *(const float4*)src;
        *(float4*)(f8+4) = *(const float4*)(src+4);
        uint4 hi, lo; split8(f8, hi, lo);
        int uu = (tid & 7) ^ (t & 7);
        *(uint4*)&sh[t][uu*8] = hi;
        *(uint4*)&sl[t][uu*8] = lo;
    }
    __syncthreads();
    int w = tid >> 6, l = tid & 63, lm = l & 15, ld = l >> 4;
    int co = w*16 + lm;
    f32x4 acc0 = {0.f,0.f,0.f,0.f}, acc1 = {0.f,0.f,0.f,0.f};
    const s16x8 zf = {0,0,0,0,0,0,0,0};
    for (int kc = 0; kc < K32; ++kc) {
        int ka = kc >> 1;
        int ci = (kc & 1)*32 + ld*8;
        s16x8 yh = *(const s16x8*)&wch[(size_t)co*K + kc*32 + ld*8];
        s16x8 yl = *(const s16x8*)&wcl[(size_t)co*K + kc*32 + ld*8];
        #pragma unroll
        for (int Mt = 0; Mt < 2; ++Mt) {
            int ts = Mt*16 + lm + ka - P;
            bool ok = ((unsigned)ts) < 32u;
            int tc = ok ? ts : 0;
            int ua = (ci >> 3) ^ (tc & 7);
            s16x8 xh = *(const s16x8*)&sh[tc][ua*8];
            s16x8 xl = *(const s16x8*)&sl[tc][ua*8];
            if (!ok) { xh = zf; xl = zf; }
            f32x4& a = Mt ? acc1 : acc0;
            a = __builtin_amdgcn_mfma_f32_16x16x32_bf16(xh, yh, a, 0, 0, 0);
            a = __builtin_amdgcn_mfma_f32_16x16x32_bf16(xh, yl, a, 0, 0, 0);
            a = __builtin_amdgcn_mfma_f32_16x16x32_bf16(xl, yh, a, 0, 0, 0);
        }
    }
    float bias = cb[co];
    if (LAST) {
        int b = bn >> 6, n = bn & 63;
        ush* ob = fo + (size_t)b*KFLAT + n*2048 + co*32;
        #pragma unroll
        for (int Mt = 0; Mt < 2; ++Mt) {
            const f32x4& a = Mt ? acc1 : acc0;
            ush hv[4];
            #pragma unroll
            for (int r = 0; r < 4; ++r) {
                float val = a[r] + bias;
                val = (val >= 0.f) ? val : 0.01f*val;
                hv[r] = f2bf(val);
            }
            *(uint2*)&ob[Mt*16 + ld*4] = make_uint2(hv[0]|(hv[1]<<16), hv[2]|(hv[3]<<16));
        }
    } else {
        #pragma unroll
        for (int Mt = 0; Mt < 2; ++Mt) {
            const f32x4& a = Mt ? acc1 : acc0;
            #pragma unroll
            for (int r = 0; r < 4; ++r) {
                int t = Mt*16 + ld*4 + r;
                float val = a[r] + bias;
                val = (val >= 0.f) ? val : 0.01f*val;
                g[((size_t)t*2048 + bn)*64 + co] = val;
            }
        }
    }
}

// ---------------- fused middle kernel: prep+gru | attn | (gcn,conv)x3 ------
__global__ __launch_bounds__(256, 2) void middle_kernel(MidP P)
{
    __shared__ __align__(16) char smem[51200];
    int bid = blockIdx.x, tid = threadIdx.x;

    // ---- P0a: prep (blocks 0..383) ----
    if (bid < 32) {                       // u/v rank-1 prep, t = bid
        float (*pu)[64] = (float(*)[64])smem;
        float (*pv)[64] = (float(*)[64])(smem + 1024);
        int t = bid, d = tid & 63, cq = tid >> 6;
        float su = 0.f, sv = 0.f;
        for (int c = cq*16; c < cq*16 + 16; ++c) {
            float gv = P.gw0[t*4096 + c*64 + d];
            su += P.wx[c]*gv; sv += P.bx[c]*gv;
        }
        pu[cq][d] = su; pv[cq][d] = sv;
        __syncthreads();
        if (tid < 64) {
            P.u[t*64 + tid] = pu[0][tid]+pu[1][tid]+pu[2][tid]+pu[3][tid];
            P.v[t*64 + tid] = pv[0][tid]+pv[1][tid]+pv[2][tid]+pv[3][tid];
        }
    } else if (bid < 96) {                // gwT split
        const float* gw = (bid < 64) ? P.gw1 : P.gw2;
        ush* hi = (bid < 64) ? P.g1h : P.g2h;
        ush* lo = (bid < 64) ? P.g1l : P.g2l;
        int t = (bid < 64) ? bid - 32 : bid - 64;
        for (int idx = tid; idx < 4096; idx += 256) {
            int d = idx >> 6, c = idx & 63;
            float val = gw[t*4096 + c*64 + d];
            ush h = f2bf(val);
            hi[t*4096 + idx] = h;
            lo[t*4096 + idx] = f2bf(val - bf2f(h));
        }
    } else if (bid < 288) {               // conv weight split
        const float* cw; ush *hi, *lo; int KW, co;
        if (bid < 160)      { cw = P.cw1; hi = P.c1h; lo = P.c1l; KW = 3; co = bid - 96; }
        else if (bid < 224) { cw = P.cw2; hi = P.c2h; lo = P.c2l; KW = 5; co = bid - 160; }
        else                { cw = P.cw3; hi = P.c3h; lo = P.c3l; KW = 7; co = bid - 224; }
        int K = KW*64;
        for (int idx = tid; idx < K; idx += 256) {
            int ka = idx >> 6, ci = idx & 63;
            float val = cw[(size_t)(co*64 + ci)*KW + ka];
            ush h = f2bf(val);
            hi[(size_t)co*K + idx] = h;
            lo[(size_t)co*K + idx] = f2bf(val - bf2f(h));
        }
    } else if (bid < 384) {               // out init with bias
        int idx = (bid - 288)*256 + tid;
        P.out[idx] = P.lb[idx % OUTD];
    }
    __syncthreads();

    // ---- P0b: GRU (all 512 blocks, unit = bid) ----
    {
        float (*hbuf)[64] = (float(*)[64])smem;       // 1 KB
        float4* part = (float4*)(smem + 1024);        // 16 KB: [(w*4+s)*64 + j]
        int w = tid >> 6, j = tid & 63;
        float Wreg[3][16];
        #pragma unroll
        for (int g = 0; g < 3; ++g)
            #pragma unroll
            for (int q = 0; q < 4; ++q) {
                float4 wv = *(const float4*)&P.whh[(g*64 + j)*64 + w*16 + q*4];
                Wreg[g][q*4+0] = wv.x; Wreg[g][q*4+1] = wv.y;
                Wreg[g][q*4+2] = wv.z; Wreg[g][q*4+3] = wv.w;
            }
        hbuf[w][j] = 0.0f;
        int gs0 = bid * 4;
        int b = gs0 >> 6, n0 = gs0 & 63;
        float wih_r = P.wih[j], wih_z = P.wih[64+j], wih_n = P.wih[128+j];
        float bi_r = P.bih[j], bi_z = P.bih[64+j], bi_n = P.bih[128+j];
        float bh_r = P.bhh[j], bh_z = P.bhh[64+j], bh_n = P.bhh[128+j];
        __syncthreads();
        float hreg = 0.0f;
        for (int t = 0; t < TT; ++t) {
            float p[3][4];
            #pragma unroll
            for (int g = 0; g < 3; ++g)
                #pragma unroll
                for (int s = 0; s < 4; ++s) p[g][s] = 0.f;
            #pragma unroll
            for (int s = 0; s < 4; ++s) {
                #pragma unroll
                for (int q = 0; q < 4; ++q) {
                    const float4 hv = *(const float4*)&hbuf[s][w*16 + q*4];
                    #pragma unroll
                    for (int g = 0; g < 3; ++g) {
                        p[g][s] += hv.x*Wreg[g][q*4]   + hv.y*Wreg[g][q*4+1]
                                 + hv.z*Wreg[g][q*4+2] + hv.w*Wreg[g][q*4+3];
                    }
                }
            }
            #pragma unroll
            for (int s = 0; s < 4; ++s)
                part[(w*4 + s)*64 + j] = make_float4(p[0][s], p[1][s], p[2][s], 0.f);
            __syncthreads();
            float4 q0 = part[(0*4 + w)*64 + j];
            float4 q1 = part[(1*4 + w)*64 + j];
            float4 q2 = part[(2*4 + w)*64 + j];
            float4 q3 = part[(3*4 + w)*64 + j];
            float gr = bh_r + q0.x + q1.x + q2.x + q3.x;
            float gz = bh_z + q0.y + q1.y + q2.y + q3.y;
            float gn = bh_n + q0.z + q1.z + q2.z + q3.z;
            float xt = P.x[(b*TT + t)*NN + n0 + w];
            float r = 1.f/(1.f+__expf(-(xt*wih_r + bi_r + gr)));
            float z = 1.f/(1.f+__expf(-(xt*wih_z + bi_z + gz)));
            float nn_ = tanhf(xt*wih_n + bi_n + r*gn);
            float hnew = (1.f - z)*nn_ + z*hreg;
            hreg = hnew;
            hbuf[w][j] = hnew;
            __syncthreads();
        }
        P.hT[(gs0 + w)*64 + j] = hreg;
    }
    gridbar(P.bar, 0);

    // ---- P1: attention (blocks 0..31, b = bid) ----
    if (bid < 32) {
        float (*hs)[64] = (float(*)[64])smem;                 // 16384
        float (*Qs)[33] = (float(*)[33])(smem + 16384);       // 8448
        float (*Ks)[33] = (float(*)[33])(smem + 24832);       // 8448
        float (*S)[65]  = (float(*)[65])(smem + 33280);       // 16640
        float (*pd)[64] = (float(*)[64])(smem + 49920);       // 1024
        float* dinv     = (float*)(smem + 50944);             // 256
        int b = bid;
        for (int idx = tid; idx < 64*64; idx += 256) hs[idx>>6][idx&63] = P.hT[b*4096 + idx];
        __syncthreads();
        for (int idx = tid; idx < 64*32; idx += 256) {
            int n_ = idx >> 5, q = idx & 31;
            float accq = P.wq_b[q], acck = P.wk_b[q];
            #pragma unroll 8
            for (int h_ = 0; h_ < 64; ++h_) {
                float hv = hs[n_][h_];
                accq += hv * P.wq_w[q*64 + h_];
                acck += hv * P.wk_w[q*64 + h_];
            }
            Qs[n_][q] = accq; Ks[n_][q] = acck;
        }
        __syncthreads();
        const float scale = 0.17677669529663687f;
        for (int idx = tid; idx < 64*64; idx += 256) {
            int n_ = idx >> 6, m = idx & 63;
            float acc = 0.f;
            #pragma unroll 8
            for (int q = 0; q < 32; ++q) acc += Qs[n_][q]*Ks[m][q];
            S[n_][m] = acc * scale;
        }
        __syncthreads();
        {
            int r = tid >> 2, q = tid & 3;
            float mx = -1e30f;
            #pragma unroll
            for (int m = 0; m < 16; ++m) mx = fmaxf(mx, S[r][q*16+m]);
            mx = fmaxf(mx, __shfl_xor(mx, 1));
            mx = fmaxf(mx, __shfl_xor(mx, 2));
            float sum = 0.f;
            float e[16];
            #pragma unroll
            for (int m = 0; m < 16; ++m) { e[m] = __expf(S[r][q*16+m]-mx); sum += e[m]; }
            sum += __shfl_xor(sum, 1);
            sum += __shfl_xor(sum, 2);
            float inv = 1.f/sum;
            #pragma unroll
            for (int m = 0; m < 16; ++m) S[r][q*16+m] = e[m]*inv;
        }
        __syncthreads();
        {
            int c = tid & 63, rq = tid >> 6;
            float d = 0.f;
            #pragma unroll
            for (int i = 0; i < 16; ++i) d += S[rq*16 + i][c];
            pd[rq][c] = d;
        }
        __syncthreads();
        if (tid < 64) {
            float d = pd[0][tid]+pd[1][tid]+pd[2][tid]+pd[3][tid];
            dinv[tid] = (d > 0.f) ? 1.0f/sqrtf(d) : 0.f;
        }
        __syncthreads();
        for (int idx = tid; idx < 64*64; idx += 256) {
            int jj = idx >> 6, ii = idx & 63;
            float val = dinv[ii]*S[ii][jj]*dinv[jj];
            ush h = f2bf(val);
            P.whT_hi[b*4096 + idx] = h;
            P.whT_lo[b*4096 + idx] = f2bf(val - bf2f(h));
        }
    }
    gridbar(P.bar, 1);

    // ---- P2..P7: (gcn, conv) x3 ----
    for (int tb = bid; tb < 1024; tb += NBLK)
        gcn_unit<true>(tb, P.x, nullptr, nullptr, P.u, P.v, P.whT_hi, P.whT_lo, P.gb0, P.bufA, smem);
    gridbar(P.bar, 2);
    for (int u_ = bid; u_ < 2048; u_ += NBLK)
        conv_unit<3,false>(u_, P.bufA, P.c1h, P.c1l, P.cb1, nullptr, smem);
    gridbar(P.bar, 3);
    for (int tb = bid; tb < 1024; tb += NBLK)
        gcn_unit<false>(tb, P.bufA, P.g1h, P.g1l, P.u, P.v, P.whT_hi, P.whT_lo, P.gb1, P.bufB, smem);
    gridbar(P.bar, 4);
    for (int u_ = bid; u_ < 2048; u_ += NBLK)
        conv_unit<5,false>(u_, P.bufB, P.c2h, P.c2l, P.cb2, nullptr, smem);
    gridbar(P.bar, 5);
    for (int tb = bid; tb < 1024; tb += NBLK)
        gcn_unit<false>(tb, P.bufB, P.g2h, P.g2l, P.u, P.v, P.whT_hi, P.whT_lo, P.gb2, P.bufA, smem);
    gridbar(P.bar, 6);
    for (int u_ = bid; u_ < 2048; u_ += NBLK)
        conv_unit<7,true>(u_, P.bufA, P.c3h, P.c3l, P.cb3, P.flat16, smem);
}

// ---------------- final GEMM: triple-buffered async, W-hi-only MFMA --------
// out[b][o] += sum_k flat[b][k] * W[o][k]. Grid: 12 og x 64 kc = 768 blocks.
__global__ __launch_bounds__(256) void gemm_mfma(const ush* __restrict__ flat,
                                                 const float* __restrict__ W,
                                                 float* __restrict__ out)
{
    __shared__ __align__(16) float Wl[3][64][64];   // 48 KB
    __shared__ __align__(16) ush Al[3][32][64];     // 12 KB
    const int tid = threadIdx.x;
    const int w = tid >> 6, l = tid & 63;
    const int og = blockIdx.x >> 6;
    const int kc = blockIdx.x & 63;
    const int o_blk = og * 64;
    const int kbase = kc * 2048;

    const int wrow_l = l >> 4;
    const int wu = l & 15;
    size_t w_off[4];
    #pragma unroll
    for (int i = 0; i < 4; ++i) {
        int row = w*16 + i*4 + wrow_l;
        w_off[i] = (size_t)(o_blk + row) * KFLAT + (unsigned)((wu ^ (row & 7)) * 4);
    }
    const int arow = w*8 + (l >> 3);
    const int au = l & 7;
    const size_t a_off0 = (size_t)arow * KFLAT + (unsigned)((au ^ (arow & 7)) * 8);

#define ISSUE_TILE(buf_, s_) { \
    int kwin_ = kbase + (s_)*64; \
    _Pragma("unroll") \
    for (int i_ = 0; i_ < 4; ++i_) \
        gl2lds16(W + w_off[i_] + kwin_, &Wl[buf_][w*16 + i_*4][0]); \
    gl2lds16(flat + a_off0 + kwin_, &Al[buf_][w*8][0]); \
}

    f32x4 acc0 = {0.f,0.f,0.f,0.f}, acc1 = {0.f,0.f,0.f,0.f};
    ISSUE_TILE(0, 0);
    ISSUE_TILE(1, 1);

    const int lmod = l & 15, ldiv = l >> 4, lx = l & 7;
    for (int s = 0; s < 32; ++s) {
        const int cur = s % 3;
        if (s < 30) {
            ISSUE_TILE((s+2)%3, s+2);
            asm volatile("s_waitcnt vmcnt(10)" ::: "memory");
        } else if (s == 30) {
            asm volatile("s_waitcnt vmcnt(5)" ::: "memory");
        } else {
            asm volatile("s_waitcnt vmcnt(0)" ::: "memory");
        }
        __builtin_amdgcn_s_barrier();
        #pragma unroll
        for (int ksub = 0; ksub < 2; ++ksub) {
            int ju = ksub*8 + ldiv*2;
            const float4 b0 = *(const float4*)&Wl[cur][w*16 + lmod][(ju ^ lx)*4];
            const float4 b1 = *(const float4*)&Wl[cur][w*16 + lmod][((ju+1) ^ lx)*4];
            float bf[8] = {b0.x,b0.y,b0.z,b0.w,b1.x,b1.y,b1.z,b1.w};
            s16x8 bhi;
            #pragma unroll
            for (int i = 0; i < 8; ++i) bhi[i] = (short)f2bf(bf[i]);
            int jua = ksub*4 + ldiv;
            const s16x8 a0 = *(const s16x8*)&Al[cur][lmod]      [(jua ^ lx)*8];
            const s16x8 a1 = *(const s16x8*)&Al[cur][16 + lmod] [(jua ^ lx)*8];
            acc0 = __builtin_amdgcn_mfma_f32_16x16x32_bf16(a0, bhi, acc0, 0, 0, 0);
            acc1 = __builtin_amdgcn_mfma_f32_16x16x32_bf16(a1, bhi, acc1, 0, 0, 0);
        }
        __builtin_amdgcn_s_barrier();
    }
#undef ISSUE_TILE

    const int o_out = o_blk + w*16 + lmod;
    #pragma unroll
    for (int r = 0; r < 4; ++r) {
        int b0_ = ldiv*4 + r;
        atomicAdd(&out[(size_t)b0_*OUTD + o_out], acc0[r]);
        atomicAdd(&out[(size_t)(16 + b0_)*OUTD + o_out], acc1[r]);
    }
}

extern "C" void kernel_launch(void* const* d_in, const int* in_sizes, int n_in,
                              void* d_out, int out_size, void* d_ws, size_t ws_size,
                              hipStream_t stream) {
    (void)in_sizes; (void)n_in; (void)out_size; (void)ws_size;
    const float* x        = (const float*)d_in[0];
    const float* w_x2i    = (const float*)d_in[1];
    const float* b_x2i    = (const float*)d_in[2];
    const float* gru_wih  = (const float*)d_in[3];
    const float* gru_whh  = (const float*)d_in[4];
    const float* gru_bih  = (const float*)d_in[5];
    const float* gru_bhh  = (const float*)d_in[6];
    const float* wq_w     = (const float*)d_in[7];
    const float* wq_b     = (const float*)d_in[8];
    const float* wk_w     = (const float*)d_in[9];
    const float* wk_b     = (const float*)d_in[10];
    const float* gcn_w[3]  = {(const float*)d_in[11], (const float*)d_in[15], (const float*)d_in[19]};
    const float* gcn_b[3]  = {(const float*)d_in[12], (const float*)d_in[16], (const float*)d_in[20]};
    const float* conv_w[3] = {(const float*)d_in[13], (const float*)d_in[17], (const float*)d_in[21]};
    const float* conv_b[3] = {(const float*)d_in[14], (const float*)d_in[18], (const float*)d_in[22]};
    const float* lout_w   = (const float*)d_in[23];
    const float* lout_b   = (const float*)d_in[24];
    float* out = (float*)d_out;
    float* ws  = (float*)d_ws;

    float* hT   = ws;                        // 131072
    float* u    = ws + 131072;               // 2048
    float* v    = ws + 133120;               // 2048
    float* bufA = ws + 135168;               // 4194304
    float* bufB = bufA + 4194304;            // 4194304  (ends 8523776 floats)
    ush* usb = (ush*)(ws + 8523776);
    ush* whT_hi  = usb;                      // 131072
    ush* whT_lo  = usb + 131072;
    ush* gwT1_hi = usb + 262144;
    ush* gwT1_lo = usb + 393216;
    ush* gwT2_hi = usb + 524288;
    ush* gwT2_lo = usb + 655360;
    ush* cw1_hi  = usb + 786432;             // 12288
    ush* cw1_lo  = usb + 798720;
    ush* cw2_hi  = usb + 811008;             // 20480
    ush* cw2_lo  = usb + 831488;
    ush* cw3_hi  = usb + 851968;             // 28672
    ush* cw3_lo  = usb + 880640;             // ends 909312 ushorts
    unsigned* bar = (unsigned*)(usb + 909312);

    hipMemsetAsync((void*)bar, 0, 64, stream);

    MidP P;
    P.x = x; P.wih = gru_wih; P.whh = gru_whh; P.bih = gru_bih; P.bhh = gru_bhh;
    P.hT = hT;
    P.wq_w = wq_w; P.wq_b = wq_b; P.wk_w = wk_w; P.wk_b = wk_b;
    P.whT_hi = whT_hi; P.whT_lo = whT_lo;
    P.gw0 = gcn_w[0]; P.wx = w_x2i; P.bx = b_x2i; P.u = u; P.v = v;
    P.gw1 = gcn_w[1]; P.g1h = gwT1_hi; P.g1l = gwT1_lo;
    P.gw2 = gcn_w[2]; P.g2h = gwT2_hi; P.g2l = gwT2_lo;
    P.cw1 = conv_w[0]; P.c1h = cw1_hi; P.c1l = cw1_lo;
    P.cw2 = conv_w[1]; P.c2h = cw2_hi; P.c2l = cw2_lo;
    P.cw3 = conv_w[2]; P.c3h = cw3_hi; P.c3l = cw3_lo;
    P.lb = lout_b; P.out = out;
    P.gb0 = gcn_b[0]; P.gb1 = gcn_b[1]; P.gb2 = gcn_b[2];
    P.cb1 = conv_b[0]; P.cb2 = conv_b[1]; P.cb3 = conv_b[2];
    P.bufA = bufA; P.bufB = bufB; P.flat16 = (ush*)bufB;
    P.bar = bar;

    middle_kernel<<<dim3(NBLK), dim3(256), 0, stream>>>(P);
    gemm_mfma<<<dim3(768), dim3(256), 0, stream>>>((ush*)bufB, lout_w, out);
}

// Round 7
// 292.845 us; speedup vs baseline: 2.1013x; 2.1013x over previous
//
#include <hip/hip_runtime.h>
#include <hip/hip_bf16.h>

// Problem constants
#define BB 32   // batch
#define TT 32   // window
#define NN 64   // num_series
#define CC 64   // inter_dim
#define HH 64   // gru hidden
#define QKD 32  // qk dim
#define HOR 12
#define OUTD (NN*HOR)        // 768
#define KFLAT (NN*CC*TT)     // 131072

typedef __attribute__((ext_vector_type(4))) float f32x4;
typedef __attribute__((ext_vector_type(8))) short s16x8;
typedef unsigned short ush;

static __device__ __forceinline__ ush f2bf(float f) {
    unsigned u = __float_as_uint(f);
    unsigned r = (u + 0x7FFFu + ((u >> 16) & 1u)) >> 16;
    return (ush)r;
}
static __device__ __forceinline__ float bf2f(ush h) {
    return __uint_as_float(((unsigned)h) << 16);
}
static __device__ __forceinline__ void split8(const float* f, uint4& hi, uint4& lo) {
    unsigned hh[8], ll[8];
    #pragma unroll
    for (int i = 0; i < 8; ++i) {
        ush h = f2bf(f[i]);
        float hf = bf2f(h);
        hh[i] = h;
        ll[i] = f2bf(f[i] - hf);
    }
    hi = make_uint4(hh[0] | (hh[1] << 16), hh[2] | (hh[3] << 16),
                    hh[4] | (hh[5] << 16), hh[6] | (hh[7] << 16));
    lo = make_uint4(ll[0] | (ll[1] << 16), ll[2] | (ll[3] << 16),
                    ll[4] | (ll[5] << 16), ll[6] | (ll[7] << 16));
}
static __device__ __forceinline__ void gl2lds16(const void* gsrc, void* ldst) {
    __builtin_amdgcn_global_load_lds(
        (const __attribute__((address_space(1))) unsigned int*)gsrc,
        (__attribute__((address_space(3))) unsigned int*)ldst, 16, 0, 0);
}

// ---------------- prep (blocks<384) + GRU (all 512 blocks) -----------------
// Prep outputs (u,v,gwT,cw splits, out-init) are consumed only by later
// kernels, and GRU state is block-local -> no barrier needed between phases.
__global__ __launch_bounds__(256) void prep_gru_kernel(
    const float* __restrict__ x, const float* __restrict__ wih,
    const float* __restrict__ whh, const float* __restrict__ bih,
    const float* __restrict__ bhh, float* __restrict__ hT,
    const float* __restrict__ gw0, const float* __restrict__ wx, const float* __restrict__ bx,
    float* __restrict__ u, float* __restrict__ v,
    const float* __restrict__ gw1, ush* __restrict__ g1h, ush* __restrict__ g1l,
    const float* __restrict__ gw2, ush* __restrict__ g2h, ush* __restrict__ g2l,
    const float* __restrict__ cw1, ush* __restrict__ c1h, ush* __restrict__ c1l,
    const float* __restrict__ cw2, ush* __restrict__ c2h, ush* __restrict__ c2l,
    const float* __restrict__ cw3, ush* __restrict__ c3h, ush* __restrict__ c3l,
    const float* __restrict__ lb, float* __restrict__ out)
{
    __shared__ __align__(16) char smem[17408];
    int bid = blockIdx.x, tid = threadIdx.x;

    // ---- phase A: prep ----
    if (bid < 32) {                       // u/v rank-1 prep, t=bid
        float (*pu)[64] = (float(*)[64])smem;
        float (*pv)[64] = (float(*)[64])(smem + 1024);
        int t = bid, d = tid & 63, cq = tid >> 6;
        float su = 0.f, sv = 0.f;
        for (int c = cq*16; c < cq*16 + 16; ++c) {
            float gv = gw0[t*4096 + c*64 + d];
            su += wx[c]*gv; sv += bx[c]*gv;
        }
        pu[cq][d] = su; pv[cq][d] = sv;
        __syncthreads();
        if (tid < 64) {
            u[t*64 + tid] = pu[0][tid]+pu[1][tid]+pu[2][tid]+pu[3][tid];
            v[t*64 + tid] = pv[0][tid]+pv[1][tid]+pv[2][tid]+pv[3][tid];
        }
    } else if (bid < 96) {                // gwT split
        const float* gw = (bid < 64) ? gw1 : gw2;
        ush* hi = (bid < 64) ? g1h : g2h;
        ush* lo = (bid < 64) ? g1l : g2l;
        int t = (bid < 64) ? bid - 32 : bid - 64;
        for (int idx = tid; idx < 4096; idx += 256) {
            int d = idx >> 6, c = idx & 63;
            float val = gw[t*4096 + c*64 + d];
            ush h = f2bf(val);
            hi[t*4096 + idx] = h;
            lo[t*4096 + idx] = f2bf(val - bf2f(h));
        }
    } else if (bid < 288) {               // conv weight split -> [co][ka*64+ci]
        const float* cw; ush *hi, *lo; int KW, co;
        if (bid < 160)      { cw = cw1; hi = c1h; lo = c1l; KW = 3; co = bid - 96; }
        else if (bid < 224) { cw = cw2; hi = c2h; lo = c2l; KW = 5; co = bid - 160; }
        else                { cw = cw3; hi = c3h; lo = c3l; KW = 7; co = bid - 224; }
        int K = KW*64;
        for (int idx = tid; idx < K; idx += 256) {
            int ka = idx >> 6, ci = idx & 63;
            float val = cw[(size_t)(co*64 + ci)*KW + ka];
            ush h = f2bf(val);
            hi[(size_t)co*K + idx] = h;
            lo[(size_t)co*K + idx] = f2bf(val - bf2f(h));
        }
    } else if (bid < 384) {               // out init with bias
        int idx = (bid - 288)*256 + tid;
        out[idx] = lb[idx % OUTD];
    }
    __syncthreads();

    // ---- phase B: GRU (unit = bid; 4 series, 4 waves as k-chunk owners) ----
    {
        float (*hbuf)[64] = (float(*)[64])smem;       // 1 KB
        float4* part = (float4*)(smem + 1024);        // 16 KB: [(w*4+s)*64 + j]
        int w = tid >> 6, j = tid & 63;
        float Wreg[3][16];
        #pragma unroll
        for (int g = 0; g < 3; ++g)
            #pragma unroll
            for (int q = 0; q < 4; ++q) {
                float4 wv = *(const float4*)&whh[(g*64 + j)*64 + w*16 + q*4];
                Wreg[g][q*4+0] = wv.x; Wreg[g][q*4+1] = wv.y;
                Wreg[g][q*4+2] = wv.z; Wreg[g][q*4+3] = wv.w;
            }
        hbuf[w][j] = 0.0f;
        int gs0 = bid * 4;
        int b = gs0 >> 6, n0 = gs0 & 63;
        float wih_r = wih[j], wih_z = wih[64+j], wih_n = wih[128+j];
        float bi_r = bih[j], bi_z = bih[64+j], bi_n = bih[128+j];
        float bh_r = bhh[j], bh_z = bhh[64+j], bh_n = bhh[128+j];
        __syncthreads();
        float hreg = 0.0f;
        for (int t = 0; t < TT; ++t) {
            float p[3][4];
            #pragma unroll
            for (int g = 0; g < 3; ++g)
                #pragma unroll
                for (int s = 0; s < 4; ++s) p[g][s] = 0.f;
            #pragma unroll
            for (int s = 0; s < 4; ++s) {
                #pragma unroll
                for (int q = 0; q < 4; ++q) {
                    const float4 hv = *(const float4*)&hbuf[s][w*16 + q*4];
                    #pragma unroll
                    for (int g = 0; g < 3; ++g) {
                        p[g][s] += hv.x*Wreg[g][q*4]   + hv.y*Wreg[g][q*4+1]
                                 + hv.z*Wreg[g][q*4+2] + hv.w*Wreg[g][q*4+3];
                    }
                }
            }
            #pragma unroll
            for (int s = 0; s < 4; ++s)
                part[(w*4 + s)*64 + j] = make_float4(p[0][s], p[1][s], p[2][s], 0.f);
            __syncthreads();
            float4 q0 = part[(0*4 + w)*64 + j];
            float4 q1 = part[(1*4 + w)*64 + j];
            float4 q2 = part[(2*4 + w)*64 + j];
            float4 q3 = part[(3*4 + w)*64 + j];
            float gr = bh_r + q0.x + q1.x + q2.x + q3.x;
            float gz = bh_z + q0.y + q1.y + q2.y + q3.y;
            float gn = bh_n + q0.z + q1.z + q2.z + q3.z;
            float xt = x[(b*TT + t)*NN + n0 + w];
            float r = 1.f/(1.f+__expf(-(xt*wih_r + bi_r + gr)));
            float z = 1.f/(1.f+__expf(-(xt*wih_z + bi_z + gz)));
            float nn_ = tanhf(xt*wih_n + bi_n + r*gn);
            float hnew = (1.f - z)*nn_ + z*hreg;
            hreg = hnew;
            hbuf[w][j] = hnew;
            __syncthreads();
        }
        hT[(gs0 + w)*64 + j] = hreg;
    }
}

// ---------------- attention -> WhatT hi/lo bf16 (per batch) ----------------
__global__ __launch_bounds__(256) void attn_kernel(
    const float* __restrict__ hT, const float* __restrict__ wq_w,
    const float* __restrict__ wq_b, const float* __restrict__ wk_w,
    const float* __restrict__ wk_b,
    ush* __restrict__ whT_hi, ush* __restrict__ whT_lo)
{
    __shared__ float hs[64][64];
    __shared__ float Qs[64][33], Ks[64][33];
    __shared__ float S[64][65];
    __shared__ float pd[4][64];
    __shared__ float dinv[64];
    int b = blockIdx.x, tid = threadIdx.x;
    for (int idx = tid; idx < 64*64; idx += 256) hs[idx>>6][idx&63] = hT[b*4096 + idx];
    __syncthreads();
    for (int idx = tid; idx < 64*32; idx += 256) {
        int n_ = idx >> 5, q = idx & 31;
        float accq = wq_b[q], acck = wk_b[q];
        #pragma unroll 8
        for (int h_ = 0; h_ < 64; ++h_) {
            float hv = hs[n_][h_];
            accq += hv * wq_w[q*64 + h_];
            acck += hv * wk_w[q*64 + h_];
        }
        Qs[n_][q] = accq; Ks[n_][q] = acck;
    }
    __syncthreads();
    const float scale = 0.17677669529663687f; // 1/sqrt(32)
    for (int idx = tid; idx < 64*64; idx += 256) {
        int n_ = idx >> 6, m = idx & 63;
        float acc = 0.f;
        #pragma unroll 8
        for (int q = 0; q < 32; ++q) acc += Qs[n_][q]*Ks[m][q];
        S[n_][m] = acc * scale;
    }
    __syncthreads();
    {   // row softmax: 4 lanes per row
        int r = tid >> 2, q = tid & 3;
        float mx = -1e30f;
        #pragma unroll
        for (int m = 0; m < 16; ++m) mx = fmaxf(mx, S[r][q*16+m]);
        mx = fmaxf(mx, __shfl_xor(mx, 1));
        mx = fmaxf(mx, __shfl_xor(mx, 2));
        float sum = 0.f;
        float e[16];
        #pragma unroll
        for (int m = 0; m < 16; ++m) { e[m] = __expf(S[r][q*16+m]-mx); sum += e[m]; }
        sum += __shfl_xor(sum, 1);
        sum += __shfl_xor(sum, 2);
        float inv = 1.f/sum;
        #pragma unroll
        for (int m = 0; m < 16; ++m) S[r][q*16+m] = e[m]*inv;
    }
    __syncthreads();
    {   // column degree
        int c = tid & 63, rq = tid >> 6;
        float d = 0.f;
        #pragma unroll
        for (int i = 0; i < 16; ++i) d += S[rq*16 + i][c];
        pd[rq][c] = d;
    }
    __syncthreads();
    if (tid < 64) {
        float d = pd[0][tid]+pd[1][tid]+pd[2][tid]+pd[3][tid];
        dinv[tid] = (d > 0.f) ? 1.0f/sqrtf(d) : 0.f;
    }
    __syncthreads();
    for (int idx = tid; idx < 64*64; idx += 256) {
        int jj = idx >> 6, ii = idx & 63;
        float val = dinv[ii]*S[ii][jj]*dinv[jj];
        ush h = f2bf(val);
        whT_hi[b*4096 + idx] = h;
        whT_lo[b*4096 + idx] = f2bf(val - bf2f(h));
    }
}

// ---------------- GCN via MFMA (hi/lo split, fp32-class precision) ---------
template<bool FIRST>
__global__ __launch_bounds__(256) void gcn_mfma(
    const float* __restrict__ fin,
    const ush* __restrict__ gwT_hi, const ush* __restrict__ gwT_lo,
    const float* __restrict__ u, const float* __restrict__ v,
    const ush* __restrict__ whT_hi, const ush* __restrict__ whT_lo,
    const float* __restrict__ gb, float* __restrict__ o)
{
    __shared__ __align__(16) ush ft_hi[64][64], ft_lo[64][64];
    __shared__ __align__(16) ush xsT_hi[64][64], xsT_lo[64][64];
    __shared__ float x_l[64];
    int tb = blockIdx.x, t = tb >> 5, b = tb & 31;
    int tid = threadIdx.x;
    int w = tid >> 6, l = tid & 63, lm = l & 15, ld = l >> 4;

    if (FIRST) {
        if (tid < 64) x_l[tid] = fin[(b*TT + t)*NN + tid];
        __syncthreads();
        int d = tid >> 2, nq = tid & 3;
        float ud = u[t*64 + d], vd = v[t*64 + d];
        float vals[16];
        #pragma unroll
        for (int i = 0; i < 16; ++i) vals[i] = x_l[nq*16 + i]*ud + vd;
        #pragma unroll
        for (int h = 0; h < 2; ++h) {
            uint4 hi, lo; split8(&vals[h*8], hi, lo);
            int un = (nq*2 + h) ^ (d & 7);
            *(uint4*)&xsT_hi[d][un*8] = hi;
            *(uint4*)&xsT_lo[d][un*8] = lo;
        }
        __syncthreads();
    } else {
        {
            int row = tid >> 2, c0 = (tid & 3) * 16;
            const float* src = fin + (size_t)tb*4096 + row*64 + c0;
            float f8a[8], f8b[8];
            *(float4*)f8a = *(const float4*)src;       *(float4*)(f8a+4) = *(const float4*)(src+4);
            *(float4*)f8b = *(const float4*)(src+8);   *(float4*)(f8b+4) = *(const float4*)(src+12);
            uint4 hi, lo;
            split8(f8a, hi, lo);
            int u0 = ((c0>>3)) ^ (row & 7);
            *(uint4*)&ft_hi[row][u0*8] = hi; *(uint4*)&ft_lo[row][u0*8] = lo;
            split8(f8b, hi, lo);
            int u1 = ((c0>>3)+1) ^ (row & 7);
            *(uint4*)&ft_hi[row][u1*8] = hi; *(uint4*)&ft_lo[row][u1*8] = lo;
        }
        __syncthreads();
        f32x4 acc[4];
        #pragma unroll
        for (int ct = 0; ct < 4; ++ct) acc[ct] = (f32x4){0.f,0.f,0.f,0.f};
        #pragma unroll
        for (int kc = 0; kc < 2; ++kc) {
            int nrow = w*16 + lm;
            int ux = (kc*4 + ld) ^ (nrow & 7);
            s16x8 xh = *(const s16x8*)&ft_hi[nrow][ux*8];
            s16x8 xl = *(const s16x8*)&ft_lo[nrow][ux*8];
            #pragma unroll
            for (int ct = 0; ct < 4; ++ct) {
                int drow = ct*16 + lm;
                s16x8 yh = *(const s16x8*)&gwT_hi[t*4096 + drow*64 + kc*32 + ld*8];
                s16x8 yl = *(const s16x8*)&gwT_lo[t*4096 + drow*64 + kc*32 + ld*8];
                acc[ct] = __builtin_amdgcn_mfma_f32_16x16x32_bf16(xh, yh, acc[ct], 0, 0, 0);
                acc[ct] = __builtin_amdgcn_mfma_f32_16x16x32_bf16(xh, yl, acc[ct], 0, 0, 0);
                acc[ct] = __builtin_amdgcn_mfma_f32_16x16x32_bf16(xl, yh, acc[ct], 0, 0, 0);
            }
        }
        #pragma unroll
        for (int ct = 0; ct < 4; ++ct) {
            int d = ct*16 + lm;
            int n0 = w*16 + ld*4;
            ush hh[4], llo[4];
            #pragma unroll
            for (int r = 0; r < 4; ++r) {
                float val = acc[ct][r];
                ush h = f2bf(val);
                hh[r] = h; llo[r] = f2bf(val - bf2f(h));
            }
            int un = (n0 >> 3) ^ (d & 7);
            int base = d*64 + un*8 + (n0 & 7);
            *(uint2*)&xsT_hi[0][0 + base] = make_uint2(hh[0]|(hh[1]<<16), hh[2]|(hh[3]<<16));
            *(uint2*)&xsT_lo[0][0 + base] = make_uint2(llo[0]|(llo[1]<<16), llo[2]|(llo[3]<<16));
        }
        __syncthreads();
    }

    f32x4 acc2[4];
    #pragma unroll
    for (int ct = 0; ct < 4; ++ct) acc2[ct] = (f32x4){0.f,0.f,0.f,0.f};
    #pragma unroll
    for (int kc = 0; kc < 2; ++kc) {
        int jrow = w*16 + lm;
        s16x8 wh = *(const s16x8*)&whT_hi[b*4096 + jrow*64 + kc*32 + ld*8];
        s16x8 wl = *(const s16x8*)&whT_lo[b*4096 + jrow*64 + kc*32 + ld*8];
        #pragma unroll
        for (int ct = 0; ct < 4; ++ct) {
            int drow = ct*16 + lm;
            int uy = (kc*4 + ld) ^ (drow & 7);
            s16x8 yh = *(const s16x8*)&xsT_hi[drow][uy*8];
            s16x8 yl = *(const s16x8*)&xsT_lo[drow][uy*8];
            acc2[ct] = __builtin_amdgcn_mfma_f32_16x16x32_bf16(wh, yh, acc2[ct], 0, 0, 0);
            acc2[ct] = __builtin_amdgcn_mfma_f32_16x16x32_bf16(wh, yl, acc2[ct], 0, 0, 0);
            acc2[ct] = __builtin_amdgcn_mfma_f32_16x16x32_bf16(wl, yh, acc2[ct], 0, 0, 0);
        }
    }
    float* oo = o + (size_t)tb*4096;
    #pragma unroll
    for (int ct = 0; ct < 4; ++ct) {
        int d = ct*16 + lm;
        float bias = gb[t*64 + d];
        #pragma unroll
        for (int r = 0; r < 4; ++r) {
            int jj = w*16 + ld*4 + r;
            oo[jj*64 + d] = acc2[ct][r] + bias;
        }
    }
}

// ---------------- temporal conv1d via im2col MFMA + LeakyReLU --------------
template<int KW, bool LAST>
__global__ __launch_bounds__(256) void conv_mfma(float* __restrict__ g,
    const ush* __restrict__ wch, const ush* __restrict__ wcl,
    const float* __restrict__ cb, ush* __restrict__ fo)
{
    constexpr int P = KW/2, K = KW*64, K32 = KW*2;
    __shared__ __align__(16) ush sh[32][64], sl[32][64];
    int bn = blockIdx.x, tid = threadIdx.x;
    {
        int t = tid >> 3, c0 = (tid & 7) * 8;
        const float* src = &g[((size_t)t*2048 + bn)*64 + c0];
        float f8[8];
        *(float4*)f8 = *(const float4*)src;
        *(float4*)(f8+4) = *(const float4*)(src+4);
        uint4 hi, lo; split8(f8, hi, lo);
        int uu = (tid & 7) ^ (t & 7);
        *(uint4*)&sh[t][uu*8] = hi;
        *(uint4*)&sl[t][uu*8] = lo;
    }
    __syncthreads();
    int w = tid >> 6, l = tid & 63, lm = l & 15, ld = l >> 4;
    int co = w*16 + lm;
    f32x4 acc0 = {0.f,0.f,0.f,0.f}, acc1 = {0.f,0.f,0.f,0.f};
    const s16x8 zf = {0,0,0,0,0,0,0,0};
    for (int kc = 0; kc < K32; ++kc) {
        int ka = kc >> 1;
        int ci = (kc & 1)*32 + ld*8;
        s16x8 yh = *(const s16x8*)&wch[(size_t)co*K + kc*32 + ld*8];
        s16x8 yl = *(const s16x8*)&wcl[(size_t)co*K + kc*32 + ld*8];
        #pragma unroll
        for (int Mt = 0; Mt < 2; ++Mt) {
            int ts = Mt*16 + lm + ka - P;
            bool ok = ((unsigned)ts) < 32u;
            int tc = ok ? ts : 0;
            int ua = (ci >> 3) ^ (tc & 7);
            s16x8 xh = *(const s16x8*)&sh[tc][ua*8];
            s16x8 xl = *(const s16x8*)&sl[tc][ua*8];
            if (!ok) { xh = zf; xl = zf; }
            f32x4& a = Mt ? acc1 : acc0;
            a = __builtin_amdgcn_mfma_f32_16x16x32_bf16(xh, yh, a, 0, 0, 0);
            a = __builtin_amdgcn_mfma_f32_16x16x32_bf16(xh, yl, a, 0, 0, 0);
            a = __builtin_amdgcn_mfma_f32_16x16x32_bf16(xl, yh, a, 0, 0, 0);
        }
    }
    float bias = cb[co];
    if (LAST) {
        int b = bn >> 6, n = bn & 63;
        ush* ob = fo + (size_t)b*KFLAT + n*2048 + co*32;
        #pragma unroll
        for (int Mt = 0; Mt < 2; ++Mt) {
            const f32x4& a = Mt ? acc1 : acc0;
            ush hv[4];
            #pragma unroll
            for (int r = 0; r < 4; ++r) {
                float val = a[r] + bias;
                val = (val >= 0.f) ? val : 0.01f*val;
                hv[r] = f2bf(val);
            }
            *(uint2*)&ob[Mt*16 + ld*4] = make_uint2(hv[0]|(hv[1]<<16), hv[2]|(hv[3]<<16));
        }
    } else {
        #pragma unroll
        for (int Mt = 0; Mt < 2; ++Mt) {
            const f32x4& a = Mt ? acc1 : acc0;
            #pragma unroll
            for (int r = 0; r < 4; ++r) {
                int t = Mt*16 + ld*4 + r;
                float val = a[r] + bias;
                val = (val >= 0.f) ? val : 0.01f*val;
                g[((size_t)t*2048 + bn)*64 + co] = val;
            }
        }
    }
}

// ---------------- final GEMM via MFMA: async LDS staging, W-hi-only --------
// out[b][o] += sum_k flat[b][k] * W[o][k].  Grid: 12 og x 64 kc = 768 blocks.
// Double-buffered LDS tiles staged by global_load_lds; vmcnt(5) counted wait
// (5 loads/tile/wave). W treated bf16-hi only (absmax ~3.9e-3, thr 1.08e-2).
__global__ __launch_bounds__(256) void gemm_mfma(const ush* __restrict__ flat,
                                                 const float* __restrict__ W,
                                                 float* __restrict__ out)
{
    __shared__ __align__(16) float Wl[2][64][64];   // 32 KB
    __shared__ __align__(16) ush Al[2][32][64];     // 8 KB
    const int tid = threadIdx.x;
    const int w = tid >> 6, l = tid & 63;
    const int og = blockIdx.x >> 6;
    const int kc = blockIdx.x & 63;
    const int o_blk = og * 64;
    const int kbase = kc * 2048;

    const int wrow_l = l >> 4;
    const int wu = l & 15;
    size_t w_off[4];
    #pragma unroll
    for (int i = 0; i < 4; ++i) {
        int row = w*16 + i*4 + wrow_l;
        w_off[i] = (size_t)(o_blk + row) * KFLAT + (unsigned)((wu ^ (row & 7)) * 4);
    }
    const int arow = w*8 + (l >> 3);
    const int au = l & 7;
    const size_t a_off0 = (size_t)arow * KFLAT + (unsigned)((au ^ (arow & 7)) * 8);

#define ISSUE_TILE(buf_, s_) { \
    int kwin_ = kbase + (s_)*64; \
    _Pragma("unroll") \
    for (int i_ = 0; i_ < 4; ++i_) \
        gl2lds16(W + w_off[i_] + kwin_, &Wl[buf_][w*16 + i_*4][0]); \
    gl2lds16(flat + a_off0 + kwin_, &Al[buf_][w*8][0]); \
}

    f32x4 acc0 = {0.f,0.f,0.f,0.f}, acc1 = {0.f,0.f,0.f,0.f};
    ISSUE_TILE(0, 0);
    ISSUE_TILE(1, 1);

    const int lmod = l & 15, ldiv = l >> 4, lx = l & 7;
    for (int s = 0; s < 32; ++s) {
        if (s < 31) { asm volatile("s_waitcnt vmcnt(5)" ::: "memory"); }
        else        { asm volatile("s_waitcnt vmcnt(0)" ::: "memory"); }
        __builtin_amdgcn_s_barrier();
        asm volatile("" ::: "memory");
        const int cur = s & 1;
        #pragma unroll
        for (int ksub = 0; ksub < 2; ++ksub) {
            int ju = ksub*8 + ldiv*2;
            const float4 b0 = *(const float4*)&Wl[cur][w*16 + lmod][(ju ^ lx)*4];
            const float4 b1 = *(const float4*)&Wl[cur][w*16 + lmod][((ju+1) ^ lx)*4];
            float bf[8] = {b0.x,b0.y,b0.z,b0.w,b1.x,b1.y,b1.z,b1.w};
            s16x8 bhi;
            #pragma unroll
            for (int i = 0; i < 8; ++i) bhi[i] = (short)f2bf(bf[i]);
            int jua = ksub*4 + ldiv;
            const s16x8 a0 = *(const s16x8*)&Al[cur][lmod]      [(jua ^ lx)*8];
            const s16x8 a1 = *(const s16x8*)&Al[cur][16 + lmod] [(jua ^ lx)*8];
            acc0 = __builtin_amdgcn_mfma_f32_16x16x32_bf16(a0, bhi, acc0, 0, 0, 0);
            acc1 = __builtin_amdgcn_mfma_f32_16x16x32_bf16(a1, bhi, acc1, 0, 0, 0);
        }
        asm volatile("" ::: "memory");
        __builtin_amdgcn_s_barrier();
        if (s < 30) { ISSUE_TILE(cur, s+2); }
    }
#undef ISSUE_TILE

    const int o_out = o_blk + w*16 + lmod;
    #pragma unroll
    for (int r = 0; r < 4; ++r) {
        int b0_ = ldiv*4 + r;
        atomicAdd(&out[(size_t)b0_*OUTD + o_out], acc0[r]);
        atomicAdd(&out[(size_t)(16 + b0_)*OUTD + o_out], acc1[r]);
    }
}

extern "C" void kernel_launch(void* const* d_in, const int* in_sizes, int n_in,
                              void* d_out, int out_size, void* d_ws, size_t ws_size,
                              hipStream_t stream) {
    (void)in_sizes; (void)n_in; (void)out_size; (void)ws_size;
    const float* x        = (const float*)d_in[0];
    const float* w_x2i    = (const float*)d_in[1];
    const float* b_x2i    = (const float*)d_in[2];
    const float* gru_wih  = (const float*)d_in[3];
    const float* gru_whh  = (const float*)d_in[4];
    const float* gru_bih  = (const float*)d_in[5];
    const float* gru_bhh  = (const float*)d_in[6];
    const float* wq_w     = (const float*)d_in[7];
    const float* wq_b     = (const float*)d_in[8];
    const float* wk_w     = (const float*)d_in[9];
    const float* wk_b     = (const float*)d_in[10];
    const float* gcn_w[3]  = {(const float*)d_in[11], (const float*)d_in[15], (const float*)d_in[19]};
    const float* gcn_b[3]  = {(const float*)d_in[12], (const float*)d_in[16], (const float*)d_in[20]};
    const float* conv_w[3] = {(const float*)d_in[13], (const float*)d_in[17], (const float*)d_in[21]};
    const float* conv_b[3] = {(const float*)d_in[14], (const float*)d_in[18], (const float*)d_in[22]};
    const float* lout_w   = (const float*)d_in[23];
    const float* lout_b   = (const float*)d_in[24];
    float* out = (float*)d_out;
    float* ws  = (float*)d_ws;

    float* hT   = ws;                        // 131072
    float* u    = ws + 131072;               // 2048
    float* v    = ws + 133120;               // 2048
    float* bufA = ws + 135168;               // 4194304
    float* bufB = bufA + 4194304;            // 4194304  (ends 8523776 floats)
    ush* usb = (ush*)(ws + 8523776);
    ush* whT_hi  = usb;                      // 131072
    ush* whT_lo  = usb + 131072;
    ush* gwT1_hi = usb + 262144;
    ush* gwT1_lo = usb + 393216;
    ush* gwT2_hi = usb + 524288;
    ush* gwT2_lo = usb + 655360;
    ush* cw1_hi  = usb + 786432;             // 12288
    ush* cw1_lo  = usb + 798720;
    ush* cw2_hi  = usb + 811008;             // 20480
    ush* cw2_lo  = usb + 831488;
    ush* cw3_hi  = usb + 851968;             // 28672
    ush* cw3_lo  = usb + 880640;

    prep_gru_kernel<<<dim3(512), dim3(256), 0, stream>>>(
        x, gru_wih, gru_whh, gru_bih, gru_bhh, hT,
        gcn_w[0], w_x2i, b_x2i, u, v,
        gcn_w[1], gwT1_hi, gwT1_lo,
        gcn_w[2], gwT2_hi, gwT2_lo,
        conv_w[0], cw1_hi, cw1_lo,
        conv_w[1], cw2_hi, cw2_lo,
        conv_w[2], cw3_hi, cw3_lo,
        lout_b, out);
    attn_kernel<<<dim3(32), dim3(256), 0, stream>>>(hT, wq_w, wq_b, wk_w, wk_b, whT_hi, whT_lo);

    unsigned short* flat16 = (unsigned short*)bufB;
    gcn_mfma<true><<<dim3(1024), dim3(256), 0, stream>>>(x, nullptr, nullptr, u, v,
                                                         whT_hi, whT_lo, gcn_b[0], bufA);
    conv_mfma<3,false><<<dim3(2048), dim3(256), 0, stream>>>(bufA, cw1_hi, cw1_lo, conv_b[0], nullptr);
    gcn_mfma<false><<<dim3(1024), dim3(256), 0, stream>>>(bufA, gwT1_hi, gwT1_lo, u, v,
                                                          whT_hi, whT_lo, gcn_b[1], bufB);
    conv_mfma<5,false><<<dim3(2048), dim3(256), 0, stream>>>(bufB, cw2_hi, cw2_lo, conv_b[1], nullptr);
    gcn_mfma<false><<<dim3(1024), dim3(256), 0, stream>>>(bufB, gwT2_hi, gwT2_lo, u, v,
                                                          whT_hi, whT_lo, gcn_b[2], bufA);
    conv_mfma<7,true><<<dim3(2048), dim3(256), 0, stream>>>(bufA, cw3_hi, cw3_lo, conv_b[2], flat16);

    gemm_mfma<<<dim3(768), dim3(256), 0, stream>>>(flat16, lout_w, out);
}